// Round 12
// baseline (78.491 us; speedup 1.0000x reference)
//
#include <hip/hip_runtime.h>
#include <hip/hip_bf16.h>

#define BB 8192
#define TT 50
#define II 50
#define HH 10
#define CC 5

typedef __attribute__((ext_vector_type(8))) short short8;
typedef __attribute__((ext_vector_type(4))) float f32x4;

struct U4 { unsigned x, y, z, w; };
__device__ __forceinline__ short8 toB(unsigned a, unsigned b, unsigned c, unsigned d) {
    U4 u{a, b, c, d};
    return __builtin_bit_cast(short8, u);
}
__device__ __forceinline__ unsigned short bfbits(float f) {
    __hip_bfloat16 h = __float2bfloat16(f);
    union { __hip_bfloat16 h; unsigned short u; } cv;
    cv.h = h;
    return cv.u;
}
__device__ __forceinline__ unsigned packbf(float a, float b) {
    return ((unsigned)bfbits(b) << 16) | (unsigned)bfbits(a);
}

__device__ __forceinline__ float fast_tanh(float x) {
    float e = __expf(2.0f * x);
    return 1.0f - 2.0f * __builtin_amdgcn_rcpf(e + 1.0f);
}

// All-reduce sum over each 16-lane row via DPP row_ror (pure VALU, no DS).
__device__ __forceinline__ float ror_sum16(float v) {
    unsigned u;
    u = __builtin_amdgcn_update_dpp(0, (int)__float_as_uint(v), 0x121, 0xf, 0xf, false);
    v += __uint_as_float(u);
    u = __builtin_amdgcn_update_dpp(0, (int)__float_as_uint(v), 0x122, 0xf, 0xf, false);
    v += __uint_as_float(u);
    u = __builtin_amdgcn_update_dpp(0, (int)__float_as_uint(v), 0x124, 0xf, 0xf, false);
    v += __uint_as_float(u);
    u = __builtin_amdgcn_update_dpp(0, (int)__float_as_uint(v), 0x128, 0xf, 0xf, false);
    v += __uint_as_float(u);
    return v;
}

// Single fused kernel. 512 blocks x 256 threads (2 blocks/CU, 8 waves/CU).
// Phase A: per-block input projection P = Wih0 . x^T + bias via MFMA (bf16),
//          t-partitioned across the 4 waves, results to LDS sp[t][b_loc][12].
// Phase B: 3-layer recurrence + FC. 16 lanes/batch; lane k owns COLUMN k of
//          all weight matrices and scalars h0_k,h1_k,h2_k. Matvec = per-lane
//          partial products + DPP rotate-reduce (VALU only, zero DS for h).
//          Layers staggered ILP3 (iter i: L0@t=i, L1@t=i-1, L2@t=i-2).
__global__ __launch_bounds__(256, 2) void k_all(
    const float* __restrict__ x, const float* __restrict__ h0all,
    const float* __restrict__ Wih0, const float* __restrict__ Whh0,
    const float* __restrict__ bih0, const float* __restrict__ bhh0,
    const float* __restrict__ Wih1, const float* __restrict__ Whh1,
    const float* __restrict__ bih1, const float* __restrict__ bhh1,
    const float* __restrict__ Wih2, const float* __restrict__ Whh2,
    const float* __restrict__ bih2, const float* __restrict__ bhh2,
    const float* __restrict__ fcw, const float* __restrict__ fcb,
    float* __restrict__ out) {
    __shared__ __align__(16) float sp[TT * 16 * 12];   // P slice [t][b_loc][j pad12], 38.4 KB
    __shared__ __align__(16) float sfc8[TT * HH * 8];  // fcw^T padded [t][j][8], 16 KB

    const int tid = threadIdx.x;
    const int bb0 = blockIdx.x * 16;

    // ---- stage padded transposed FC weights ----
    for (int idx = tid; idx < TT * HH * 8; idx += 256) {
        int r = idx >> 3, c = idx & 7;
        sfc8[idx] = (c < CC) ? fcw[(size_t)c * (TT * HH) + r] : 0.0f;
    }

    // ================= Phase A: projection via MFMA =================
    {
        const int w = tid >> 6;        // wave id 0..3 -> t range
        const int lane = tid & 63;
        const int bl = lane & 15;      // batch col
        const int g = lane >> 4;

        short8 A0, A1;                 // Wih0 rows, k = g*8+e and 32+g*8+e
#pragma unroll
        for (int e = 0; e < 8; e++) {
            int k0 = g * 8 + e;
            int k1 = 32 + g * 8 + e;
            float v0 = (bl < HH) ? Wih0[bl * II + k0] : 0.0f;
            float v1 = (bl < HH && k1 < II) ? Wih0[bl * II + k1] : 0.0f;
            A0[e] = (short)bfbits(v0);
            A1[e] = (short)bfbits(v1);
        }
        f32x4 bc;                      // bias C-frag (row j = g*4+r)
#pragma unroll
        for (int r = 0; r < 4; r++) {
            int j = g * 4 + r;
            bc[r] = (j < HH) ? (bih0[j] + bhh0[j]) : 0.0f;
        }

#pragma unroll 1
        for (int tt = 0; tt < 13; tt++) {
            int t = w * 13 + tt;
            if (t < TT) {
                const float* xb = x + (size_t)(bb0 + bl) * (TT * II) + t * II;
                // B0: k = g*8 .. g*8+7 (all < 32 < 50), 8B-aligned float2 loads
                float2 q0 = *(const float2*)(xb + g * 8);
                float2 q1 = *(const float2*)(xb + g * 8 + 2);
                float2 q2 = *(const float2*)(xb + g * 8 + 4);
                float2 q3 = *(const float2*)(xb + g * 8 + 6);
                short8 B0 = toB(packbf(q0.x, q0.y), packbf(q1.x, q1.y),
                                packbf(q2.x, q2.y), packbf(q3.x, q3.y));
                // B1: k = 32+g*8 .. +7 (valid < 50)
                float xv[8] = {0.f, 0.f, 0.f, 0.f, 0.f, 0.f, 0.f, 0.f};
                if (g < 2) {
                    float2 a = *(const float2*)(xb + 32 + g * 8);
                    float2 b2 = *(const float2*)(xb + 34 + g * 8);
                    float2 c = *(const float2*)(xb + 36 + g * 8);
                    float2 d = *(const float2*)(xb + 38 + g * 8);
                    xv[0] = a.x; xv[1] = a.y; xv[2] = b2.x; xv[3] = b2.y;
                    xv[4] = c.x; xv[5] = c.y; xv[6] = d.x; xv[7] = d.y;
                } else if (g == 2) {
                    float2 a = *(const float2*)(xb + 48);
                    xv[0] = a.x; xv[1] = a.y;
                }
                short8 B1 = toB(packbf(xv[0], xv[1]), packbf(xv[2], xv[3]),
                                packbf(xv[4], xv[5]), packbf(xv[6], xv[7]));
                f32x4 D = __builtin_amdgcn_mfma_f32_16x16x32_bf16(A0, B0, bc, 0, 0, 0);
                D = __builtin_amdgcn_mfma_f32_16x16x32_bf16(A1, B1, D, 0, 0, 0);
                if (g < 3) {   // rows j = g*4..g*4+3 <= 11 fit in pad-12
                    float* dst = &sp[(t * 16 + bl) * 12 + g * 4];
                    float2 d01; d01.x = D[0]; d01.y = D[1];
                    float2 d23; d23.x = D[2]; d23.y = D[3];
                    *(float2*)dst = d01;
                    *(float2*)(dst + 2) = d23;
                }
            }
        }
    }

    // ================= Phase B setup =================
    const int k = tid & 15;          // column owner / row selector
    const int g16 = tid >> 4;        // batch group 0..15
    const int b = bb0 + g16;
    const bool kv = (k < HH);

    float w0c[HH], wi1c[HH], wh1c[HH], wi2c[HH], wh2c[HH], sel[HH];
    float bs1 = 0.0f, bs2 = 0.0f, h1i = 0.0f, h2i = 0.0f, h0i = 0.0f;
#pragma unroll
    for (int j = 0; j < HH; j++) {
        w0c[j]  = kv ? Whh0[j * HH + k] : 0.0f;
        wi1c[j] = kv ? Wih1[j * HH + k] : 0.0f;
        wh1c[j] = kv ? Whh1[j * HH + k] : 0.0f;
        wi2c[j] = kv ? Wih2[j * HH + k] : 0.0f;
        wh2c[j] = kv ? Whh2[j * HH + k] : 0.0f;
        sel[j] = (k == j) ? 1.0f : 0.0f;
    }
    if (kv) {
        bs1 = bih1[k] + bhh1[k];
        bs2 = bih2[k] + bhh2[k];
        h0i = h0all[(size_t)b * HH + k];
        h1i = h0all[(size_t)BB * HH + (size_t)b * HH + k];
        h2i = h0all[(size_t)2 * BB * HH + (size_t)b * HH + k];
    }
    float h0 = h0i, h1 = h1i, h2 = h2i;
    float acc[CC] = {0.0f, 0.0f, 0.0f, 0.0f, 0.0f};

    __syncthreads();   // sp + sfc8 ready

    float pcur = kv ? sp[(0 * 16 + g16) * 12 + k] : 0.0f;

#pragma unroll 1
    for (int i = 0; i < TT + 2; i++) {
        // prefetch next P (LDS, 1-iter slack)
        int tp = (i + 1 < TT) ? (i + 1) : (TT - 1);
        float pn = kv ? sp[(tp * 16 + g16) * 12 + k] : 0.0f;
        // FC weights for t = i-2
        int tauc = (i >= 2) ? (i - 2) : 0;
        float4 f4v = {0.f, 0.f, 0.f, 0.f};
        float f1v = 0.0f;
        if (kv) {
            const float* fb = &sfc8[(tauc * HH + k) * 8];
            f4v = *(const float4*)fb;
            f1v = fb[4];
        }

        float r[HH];
        // ---- L0 @ t=i : partials, rotate-reduce, select, tanh ----
#pragma unroll
        for (int j = 0; j < HH; j++) r[j] = ror_sum16(w0c[j] * h0);
        float a0 = pcur;
#pragma unroll
        for (int j = 0; j < HH; j++) a0 = fmaf(sel[j], r[j], a0);
        float t0 = fast_tanh(a0);
        // ---- L1 @ t=i-1 (uses entry h0, h1) ----
#pragma unroll
        for (int j = 0; j < HH; j++) r[j] = ror_sum16(fmaf(wh1c[j], h1, wi1c[j] * h0));
        float a1 = bs1;
#pragma unroll
        for (int j = 0; j < HH; j++) a1 = fmaf(sel[j], r[j], a1);
        float t1 = fast_tanh(a1);
        // ---- L2 @ t=i-2 (uses entry h1, h2) ----
#pragma unroll
        for (int j = 0; j < HH; j++) r[j] = ror_sum16(fmaf(wh2c[j], h2, wi2c[j] * h1));
        float a2 = bs2;
#pragma unroll
        for (int j = 0; j < HH; j++) a2 = fmaf(sel[j], r[j], a2);
        float t2 = fast_tanh(a2);

        // ---- FC accumulate for t = i-2 ----
        if (i >= 2 && kv) {
            float rl = fmaxf(t2, 0.0f);
            acc[0] = fmaf(f4v.x, rl, acc[0]);
            acc[1] = fmaf(f4v.y, rl, acc[1]);
            acc[2] = fmaf(f4v.z, rl, acc[2]);
            acc[3] = fmaf(f4v.w, rl, acc[3]);
            acc[4] = fmaf(f1v,  rl, acc[4]);
        }

        // ---- commit (init overrides during pipeline fill) ----
        h0 = t0;
        h1 = (i == 0) ? h1i : t1;
        h2 = (i <= 1) ? h2i : t2;
        pcur = pn;
    }

    // reduce acc across the 16-lane group (lanes k>=10 hold zeros)
#pragma unroll
    for (int c = 0; c < CC; c++) {
        float a = acc[c];
        a += __shfl_xor(a, 1);
        a += __shfl_xor(a, 2);
        a += __shfl_xor(a, 4);
        a += __shfl_xor(a, 8);
        acc[c] = a + fcb[c];
    }
    if (k == 0) {
#pragma unroll
        for (int c = 0; c < CC; c++) out[(size_t)b * CC + c] = acc[c];
    }
}

extern "C" void kernel_launch(void* const* d_in, const int* in_sizes, int n_in,
                              void* d_out, int out_size, void* d_ws, size_t ws_size,
                              hipStream_t stream) {
    const float* x    = (const float*)d_in[0];
    const float* h0   = (const float*)d_in[1];
    const float* Wih0 = (const float*)d_in[2];
    const float* Whh0 = (const float*)d_in[3];
    const float* bih0 = (const float*)d_in[4];
    const float* bhh0 = (const float*)d_in[5];
    const float* Wih1 = (const float*)d_in[6];
    const float* Whh1 = (const float*)d_in[7];
    const float* bih1 = (const float*)d_in[8];
    const float* bhh1 = (const float*)d_in[9];
    const float* Wih2 = (const float*)d_in[10];
    const float* Whh2 = (const float*)d_in[11];
    const float* bih2 = (const float*)d_in[12];
    const float* bhh2 = (const float*)d_in[13];
    const float* fcw  = (const float*)d_in[14];
    const float* fcb  = (const float*)d_in[15];
    float* out = (float*)d_out;

    k_all<<<BB / 16, 256, 0, stream>>>(x, h0, Wih0, Whh0, bih0, bhh0,
                                       Wih1, Whh1, bih1, bhh1,
                                       Wih2, Whh2, bih2, bhh2, fcw, fcb, out);
}

// Round 13
// 74.190 us; speedup vs baseline: 1.0580x; 1.0580x over previous
//
#include <hip/hip_runtime.h>

#define BB 8192
#define TT 50
#define II 50
#define HH 10
#define CC 5

__device__ __forceinline__ float fast_tanh(float x) {
    float e = __expf(2.0f * x);
    return 1.0f - 2.0f * __builtin_amdgcn_rcpf(e + 1.0f);
}

// One-lane rotation within each 16-lane row (pure VALU DPP; direction probed).
__device__ __forceinline__ float rot1(float v) {
    return __uint_as_float((unsigned)__builtin_amdgcn_update_dpp(
        0, (int)__float_as_uint(v), 0x121 /*row_ror:1*/, 0xF, 0xF, false));
}
__device__ __forceinline__ int rot1_i(int v) {
    return __builtin_amdgcn_update_dpp(0, v, 0x121, 0xF, 0xF, false);
}

// K1: P[t][j][b] = sum_i x[b][t][i] * Wih0[j][i] + (bih0[j]+bhh0[j])
__global__ __launch_bounds__(256) void k_proj0(
    const float* __restrict__ x, const float* __restrict__ Wih0,
    const float* __restrict__ bih0, const float* __restrict__ bhh0,
    float* __restrict__ P) {
    int gid = blockIdx.x * 256 + threadIdx.x;
    int b = gid & (BB - 1);
    int t = gid >> 13;
    const float2* xr = (const float2*)(x + ((size_t)b * TT + t) * II);
    float2 xv[II / 2];
#pragma unroll
    for (int i = 0; i < II / 2; i++) xv[i] = xr[i];
#pragma unroll
    for (int j = 0; j < HH; j++) {
        float a = bih0[j] + bhh0[j];
        const float2* w = (const float2*)(Wih0 + j * II);
#pragma unroll
        for (int i = 0; i < II / 2; i++) {
            float2 wv = w[i];
            a = fmaf(wv.x, xv[i].x, a);
            a = fmaf(wv.y, xv[i].y, a);
        }
        P[((size_t)t * HH + j) * BB + b] = a;
    }
}

// K2: fused 3-layer recurrence + FC, pure f32, SYSTOLIC DPP matvec.
// 16 lanes/batch; lane j holds h?[j] in registers. Matvec: 16 rotation steps,
// each = 3 DPP row_ror:1 + 5 FMA with pre-permuted weights. Row sums land
// directly in lane j (no reduce, no broadcast, zero DS for h).
// Layers staggered ILP3 (iter i: L0@t=i, L1@t=i-1, L2@t=i-2), register state.
__global__ __launch_bounds__(256, 2) void k_fused(
    const float* __restrict__ h0all,
    const float* __restrict__ Whh0,
    const float* __restrict__ Wih1, const float* __restrict__ Whh1,
    const float* __restrict__ bih1, const float* __restrict__ bhh1,
    const float* __restrict__ Wih2, const float* __restrict__ Whh2,
    const float* __restrict__ bih2, const float* __restrict__ bhh2,
    const float* __restrict__ fcw, const float* __restrict__ fcb,
    const float* __restrict__ P, float* __restrict__ out) {
    __shared__ __align__(16) float sfc8[(TT * HH + 8) * 8];  // padded: j<=15 reads stay in-bounds

    const int tid = threadIdx.x;
    const int j = tid & 15;
    const int g16 = tid >> 4;
    const int b = blockIdx.x * 16 + g16;
    const bool jv = (j < HH);

    // stage padded transposed FC weights: sfc8[(t*HH+j)*8 + c] = fcw[c][t*HH+j]
    for (int idx = tid; idx < TT * HH * 8; idx += 256) {
        int r = idx >> 3, c = idx & 7;
        sfc8[idx] = (c < CC) ? fcw[(size_t)c * (TT * HH) + r] : 0.0f;
    }
    for (int idx = TT * HH * 8 + tid; idx < (TT * HH + 8) * 8; idx += 256)
        sfc8[idx] = 0.0f;

    // ---- rotation-direction probe (integer-exact, wave-uniform result) ----
    // After rot1: lane j holds old lane (j+d)&15 with d = +1 or -1 (HW-defined).
    const int q = rot1_i(j) & 15;
    const bool dplus = (q == ((j + 1) & 15));

    // ---- pre-permuted systolic weights: wXs[r] = W[j][(j + d*r)&15] ----
    float w0s[16], wi1s[16], wh1s[16], wi2s[16], wh2s[16];
#pragma unroll
    for (int r = 0; r < 16; r++) {
        int k = dplus ? ((j + r) & 15) : ((j - r) & 15);
        bool v = jv && (k < HH);
        float a = 0.f, bw = 0.f, c = 0.f, d = 0.f, e = 0.f;
        if (v) {
            a = Whh0[j * HH + k];
            bw = Wih1[j * HH + k];
            c = Whh1[j * HH + k];
            d = Wih2[j * HH + k];
            e = Whh2[j * HH + k];
        }
        w0s[r] = a; wi1s[r] = bw; wh1s[r] = c; wi2s[r] = d; wh2s[r] = e;
    }
    float bs1 = 0.0f, bs2 = 0.0f, h0i = 0.0f, h1i = 0.0f, h2i = 0.0f;
    if (jv) {
        bs1 = bih1[j] + bhh1[j];
        bs2 = bih2[j] + bhh2[j];
        h0i = h0all[(size_t)b * HH + j];
        h1i = h0all[(size_t)BB * HH + (size_t)b * HH + j];
        h2i = h0all[(size_t)2 * BB * HH + (size_t)b * HH + j];
    }

    __syncthreads();   // sfc8 ready

    float h0 = h0i, h1 = h1i, h2 = h2i;
    float acc[CC] = {0.0f, 0.0f, 0.0f, 0.0f, 0.0f};

    // 2-deep P rotation (proven in R10): pc = P[t=i], p1 = P[t=i+1]
    float pc = jv ? P[(size_t)j * BB + b] : 0.0f;
    float p1 = jv ? P[(size_t)(1 * HH + j) * BB + b] : 0.0f;

#pragma unroll 1
    for (int i = 0; i < TT + 2; i++) {
        // prefetch P for t = i+2 (clamped; jv-gated: j>=10 would be OOB)
        int tp = (i + 2 < TT) ? (i + 2) : (TT - 1);
        float p2 = jv ? P[(size_t)(tp * HH + j) * BB + b] : 0.0f;

        // FC weights for t = i-2 (padded array: safe for j up to 15)
        int tauc = (i >= 2) ? (i - 2) : 0;
        const float* fb = &sfc8[(tauc * HH + j) * 8];
        float4 f4 = *(const float4*)fb;
        float  f1 = fb[4];

        // ---- systolic matvec: 16 steps, 3 rotations + 5 FMA each ----
        float a0 = pc, a1 = bs1, a2 = bs2;
        float r0 = h0, r1 = h1, r2 = h2;
#pragma unroll
        for (int r = 0; r < 16; r++) {
            a0 = fmaf(w0s[r],  r0, a0);
            a1 = fmaf(wi1s[r], r0, a1);
            a1 = fmaf(wh1s[r], r1, a1);
            a2 = fmaf(wi2s[r], r1, a2);
            a2 = fmaf(wh2s[r], r2, a2);
            if (r < 15) { r0 = rot1(r0); r1 = rot1(r1); r2 = rot1(r2); }
        }
        float t0 = fast_tanh(a0);
        float t1 = fast_tanh(a1);
        float t2 = fast_tanh(a2);

        // ---- FC accumulate for t = i-2 (t2 == 0 for lanes j>=10) ----
        if (i >= 2) {
            float rl = fmaxf(t2, 0.0f);
            acc[0] = fmaf(f4.x, rl, acc[0]);
            acc[1] = fmaf(f4.y, rl, acc[1]);
            acc[2] = fmaf(f4.z, rl, acc[2]);
            acc[3] = fmaf(f4.w, rl, acc[3]);
            acc[4] = fmaf(f1,  rl, acc[4]);
        }

        // ---- commit (init overrides during pipeline fill) ----
        h0 = t0;
        h1 = (i == 0) ? h1i : t1;
        h2 = (i <= 1) ? h2i : t2;
        pc = p1;
        p1 = p2;
    }

    // reduce acc across the 16-lane group (lanes j>=10 hold zeros)
#pragma unroll
    for (int c = 0; c < CC; c++) {
        float a = acc[c];
        a += __shfl_xor(a, 1);
        a += __shfl_xor(a, 2);
        a += __shfl_xor(a, 4);
        a += __shfl_xor(a, 8);
        acc[c] = a + fcb[c];
    }
    if (j == 0) {
#pragma unroll
        for (int c = 0; c < CC; c++) out[(size_t)b * CC + c] = acc[c];
    }
}

extern "C" void kernel_launch(void* const* d_in, const int* in_sizes, int n_in,
                              void* d_out, int out_size, void* d_ws, size_t ws_size,
                              hipStream_t stream) {
    const float* x    = (const float*)d_in[0];
    const float* h0   = (const float*)d_in[1];
    const float* Wih0 = (const float*)d_in[2];
    const float* Whh0 = (const float*)d_in[3];
    const float* bih0 = (const float*)d_in[4];
    const float* bhh0 = (const float*)d_in[5];
    const float* Wih1 = (const float*)d_in[6];
    const float* Whh1 = (const float*)d_in[7];
    const float* bih1 = (const float*)d_in[8];
    const float* bhh1 = (const float*)d_in[9];
    const float* Wih2 = (const float*)d_in[10];
    const float* Whh2 = (const float*)d_in[11];
    const float* bih2 = (const float*)d_in[12];
    const float* bhh2 = (const float*)d_in[13];
    const float* fcw  = (const float*)d_in[14];
    const float* fcb  = (const float*)d_in[15];
    float* out = (float*)d_out;
    float* P   = (float*)d_ws;   // [T][H][B] = 16.38 MB

    k_proj0<<<(BB * TT) / 256, 256, 0, stream>>>(x, Wih0, bih0, bhh0, P);
    k_fused<<<BB / 16, 256, 0, stream>>>(h0, Whh0, Wih1, Whh1, bih1, bhh1,
                                         Wih2, Whh2, bih2, bhh2, fcw, fcb, P, out);
}